// Round 8
// baseline (246.027 us; speedup 1.0000x reference)
//
#include <hip/hip_runtime.h>

typedef __bf16 bf16_t;
typedef __bf16 bf16x4 __attribute__((ext_vector_type(4)));
typedef __bf16 bf16x8 __attribute__((ext_vector_type(8)));
typedef float f32x4 __attribute__((ext_vector_type(4)));
typedef float f32x16 __attribute__((ext_vector_type(16)));

#define N_PIX 4096
#define CFEAT 256
#define CKEY 32
#define NBATCH 4
#define LOG2E 1.4426950408889634f

static __device__ __forceinline__ f32x4 mfma16(bf16x8 a, bf16x8 b, f32x4 c) {
    return __builtin_amdgcn_mfma_f32_16x16x32_bf16(a, b, c, 0, 0, 0);
}
static __device__ __forceinline__ f32x16 mfma32(bf16x8 a, bf16x8 b, f32x16 c) {
    return __builtin_amdgcn_mfma_f32_32x32x16_bf16(a, b, c, 0, 0, 0);
}
static __device__ __forceinline__ void glds16(const void* g, void* l) {
    __builtin_amdgcn_global_load_lds(
        (const __attribute__((address_space(1))) void*)g,
        (__attribute__((address_space(3))) void*)l, 16, 0, 0);
}
static __device__ __forceinline__ float fexp2(float x) {
#if __has_builtin(__builtin_amdgcn_exp2f)
    return __builtin_amdgcn_exp2f(x);   // v_exp_f32: D = 2^S0
#else
    return exp2f(x);
#endif
}

// ---------------------------------------------------------------------------
// projqk (r5 structure + log2e fold on Q): Yt[b][n][32] = bf16(s*(W.X + bias)).
// grid (N/64, 2, B), block 256. LDS repack -> coalesced 16B stores.
// ---------------------------------------------------------------------------
__global__ __launch_bounds__(256) void projqk_kernel(
    const float* __restrict__ Wq, const float* __restrict__ bq, const float* __restrict__ Xq,
    const float* __restrict__ Wk, const float* __restrict__ bk, const float* __restrict__ Xk,
    bf16_t* __restrict__ Qt, bf16_t* __restrict__ Kt)
{
    __shared__ __attribute__((aligned(16))) bf16_t T[64][40];  // [n_local][ck], +8 pad
    const int lane = threadIdx.x & 63, wave = threadIdx.x >> 6;
    const int g = lane >> 4, ln = lane & 15;
    const bool isK = (blockIdx.y == 1);
    const float* W    = isK ? Wk : Wq;
    const float* bias = isK ? bk : bq;
    const float scale = isK ? 1.0f : LOG2E;   // Q pre-scaled so pv uses exp2
    const float* X  = (isK ? Xk : Xq) + (size_t)blockIdx.z * CFEAT * N_PIX;
    bf16_t*      Yt = (isK ? Kt : Qt) + (size_t)blockIdx.z * N_PIX * CKEY;

    const int m_base = (wave & 1) * 16;                      // ck half
    const int n_loc  = (wave >> 1) * 32;                     // n half within block
    const int n_base = blockIdx.x * 64 + n_loc;

    f32x4 zero = {0.f, 0.f, 0.f, 0.f};
    f32x4 acc[2] = {zero, zero};
    for (int k0 = 0; k0 < CFEAT; k0 += 32) {
        bf16x8 a;
        const float* wp = W + (size_t)(m_base + ln) * CFEAT + k0 + g * 8;
#pragma unroll
        for (int j = 0; j < 8; ++j) a[j] = (bf16_t)wp[j];
#pragma unroll
        for (int nt = 0; nt < 2; ++nt) {
            const float* xp = X + (size_t)(k0 + g * 8) * N_PIX + n_base + nt * 16 + ln;
            bf16x8 bfr;
#pragma unroll
            for (int j = 0; j < 8; ++j) bfr[j] = (bf16_t)xp[(size_t)j * N_PIX];
            acc[nt] = mfma16(a, bfr, acc[nt]);
        }
    }
#pragma unroll
    for (int nt = 0; nt < 2; ++nt)
#pragma unroll
        for (int r = 0; r < 4; ++r) {
            const int ck = m_base + g * 4 + r;
            T[n_loc + nt * 16 + ln][ck] = (bf16_t)((acc[nt][r] + bias[ck]) * scale);
        }
    __syncthreads();
    const int n  = threadIdx.x >> 2;
    const int sg = threadIdx.x & 3;
    bf16x8 row = *(const bf16x8*)&T[n][sg * 8];
    *(bf16x8*)&Yt[(size_t)(blockIdx.x * 64 + n) * CKEY + sg * 8] = row;
}

// ---------------------------------------------------------------------------
// projv (r5 verbatim): V[b][c][n] = bf16(Wv.X + bv). grid (N/32, 2, B).
// ---------------------------------------------------------------------------
__global__ __launch_bounds__(256, 4) void projv_kernel(
    const float* __restrict__ W, const float* __restrict__ bias,
    const float* __restrict__ X, bf16_t* __restrict__ V)
{
    const int lane = threadIdx.x & 63, wave = threadIdx.x >> 6;
    const int g = lane >> 4, ln = lane & 15;
    const int b = blockIdx.z;
    const int n_base = blockIdx.x * 32;
    const int c_wave = blockIdx.y * 128 + wave * 32;
    const float* Xb = X + (size_t)b * CFEAT * N_PIX;
    bf16_t*      Vb = V + (size_t)b * CFEAT * N_PIX;

    f32x4 zero = {0.f, 0.f, 0.f, 0.f};
    f32x4 acc[2][2];
#pragma unroll
    for (int mt = 0; mt < 2; ++mt) { acc[mt][0] = zero; acc[mt][1] = zero; }

    for (int k0 = 0; k0 < CFEAT; k0 += 32) {
        bf16x8 bfr[2];
#pragma unroll
        for (int nt = 0; nt < 2; ++nt) {
            const float* xp = Xb + (size_t)(k0 + g * 8) * N_PIX + n_base + nt * 16 + ln;
#pragma unroll
            for (int j = 0; j < 8; ++j) bfr[nt][j] = (bf16_t)xp[(size_t)j * N_PIX];
        }
#pragma unroll
        for (int mt = 0; mt < 2; ++mt) {
            const float* wp = W + (size_t)(c_wave + mt * 16 + ln) * CFEAT + k0 + g * 8;
            bf16x8 a;
#pragma unroll
            for (int j = 0; j < 8; ++j) a[j] = (bf16_t)wp[j];
            acc[mt][0] = mfma16(a, bfr[0], acc[mt][0]);
            acc[mt][1] = mfma16(a, bfr[1], acc[mt][1]);
        }
    }
#pragma unroll
    for (int mt = 0; mt < 2; ++mt)
#pragma unroll
        for (int nt = 0; nt < 2; ++nt)
#pragma unroll
            for (int r = 0; r < 4; ++r) {
                const int m = c_wave + mt * 16 + g * 4 + r;
                const int n = n_base + nt * 16 + ln;
                Vb[(size_t)m * N_PIX + n] = (bf16_t)(acc[mt][nt][r] + bias[m]);
            }
}

// ---------------------------------------------------------------------------
// pv: out = gamma * softmax(QK^T).V / l + feat (max-free, exp2; Q pre-scaled).
// All-mfma32 version: halves LDS fragment traffic per FLOP (the r5/r7 limiter)
// and halves S/exp redundancy. Block 64i x 64c, 4 waves of 32i x 32c
// (iw = wave>>1, cw = wave&1). grid (4 c-splits, 64 i-tiles, B) = 1024
// -> 4 blocks/CU, 16 waves/CU (r5's winning co-residency).
// V tile 64c x 64j staged via glds16 into chunk-major [jc][c] (16B chunks,
// linear b128 reads), double-buffered, glds issued AFTER the barrier.
// P wave-private LDS, chunk-major [jc][i]. Per-lane stats (S^T: D col = i).
// ---------------------------------------------------------------------------
__global__ __launch_bounds__(256, 4) void pv_kernel(
    const bf16_t* __restrict__ Qt, const bf16_t* __restrict__ Kt,
    const bf16_t* __restrict__ V,
    const float* __restrict__ features, const float* __restrict__ gamma,
    float* __restrict__ out)
{
    __shared__ __attribute__((aligned(16))) bf16_t Vlds[2][64 * 64];  // 2 x 8KB
    __shared__ __attribute__((aligned(16))) bf16_t Plds[4][2048];     // 4KB/wave

    const int lane = threadIdx.x & 63, wave = threadIdx.x >> 6;
    const int l31 = lane & 31, h = lane >> 5;
    const int iw = wave >> 1, cw = wave & 1;
    const int b = blockIdx.z;
    const int i0 = blockIdx.y * 64 + iw * 32;      // wave's 32 i
    const int c_blk = blockIdx.x * 64;
    const int c_off = cw * 32;                     // wave's c within tile

    const bf16_t* Qb = Qt + (size_t)b * N_PIX * CKEY;
    const bf16_t* Kb = Kt + (size_t)b * N_PIX * CKEY;
    const bf16_t* Vb = V + (size_t)b * CFEAT * N_PIX;
    bf16_t* Pw = &Plds[wave][0];

    // Q B-frags (hoisted): B[k=ck=s*16+h*8+j][n=i=l31] = Qt[i][ck]
    bf16x8 qf[2];
#pragma unroll
    for (int s = 0; s < 2; ++s)
        qf[s] = *(const bf16x8*)&Qb[(size_t)(i0 + l31) * CKEY + s * 16 + h * 8];

    // V staging: call q stages chunk jc = wave*2+q (uniform), c = lane.
    const bf16_t* vs0 = Vb + (size_t)(c_blk + lane) * N_PIX + (wave * 2 + 0) * 8;
    const bf16_t* vs1 = Vb + (size_t)(c_blk + lane) * N_PIX + (wave * 2 + 1) * 8;
    const int d0 = (wave * 2 + 0) * 512;   // LDS element offsets (uniform)
    const int d1 = (wave * 2 + 1) * 512;

    f32x16 acc;
#pragma unroll
    for (int r = 0; r < 16; ++r) acc[r] = 0.f;
    float lsum = 0.f;

    // prologue: stage V(0) -> buf 0
    glds16(vs0, &Vlds[0][d0]);
    glds16(vs1, &Vlds[0][d1]);

    for (int n = 0; n < 64; ++n) {
        const int j0 = n * 64;
        // ---- S^T(n): two 32j x 32i tiles, k=ck=32 as 2 mfma32 steps ----
        f32x16 st[2];
#pragma unroll
        for (int jt = 0; jt < 2; ++jt) {
            f32x16 z;
#pragma unroll
            for (int r = 0; r < 16; ++r) z[r] = 0.f;
            const bf16_t* kp = &Kb[(size_t)(j0 + jt * 32 + l31) * CKEY + h * 8];
            const bf16x8 kf0 = *(const bf16x8*)kp;
            const bf16x8 kf1 = *(const bf16x8*)(kp + 16);
            st[jt] = mfma32(kf1, qf[1], mfma32(kf0, qf[0], z));
        }
        // ---- exp2 -> P chunks [jc=jt*4+q][i=l31], 8B offset h*4 ----
#pragma unroll
        for (int jt = 0; jt < 2; ++jt)
#pragma unroll
            for (int q = 0; q < 4; ++q) {
                bf16x4 p;
#pragma unroll
                for (int r = 0; r < 4; ++r) {
                    const float e = fexp2(st[jt][q * 4 + r]);
                    lsum += e;
                    p[r] = (bf16_t)e;
                }
                *(bf16x4*)&Pw[((jt * 4 + q) * 32 + l31) * 8 + h * 4] = p;
            }
        // ---- P B-frags: k-step s -> chunk (s*2+h, i=l31), linear b128 ----
        bf16x8 pa[4];
#pragma unroll
        for (int s = 0; s < 4; ++s)
            pa[s] = *(const bf16x8*)&Pw[((s * 2 + h) * 32 + l31) * 8];

        // ---- barrier: drains V(n) DMA + recycles buffers ----
        __syncthreads();
        const int jn = (j0 + 64) & (N_PIX - 1);   // wrap on last iter: unused
        const int bn = (n + 1) & 1;
        glds16(vs0 + jn, &Vlds[bn][d0]);
        glds16(vs1 + jn, &Vlds[bn][d1]);

        // ---- PV(n): A = V chunk (s*2+h, c=c_off+l31), 4 mfma32 ----
        const bf16_t* Vt = &Vlds[n & 1][0];
#pragma unroll
        for (int s = 0; s < 4; ++s) {
            const bf16x8 va = *(const bf16x8*)&Vt[((s * 2 + h) * 64 + c_off + l31) * 8];
            acc = mfma32(va, pa[s], acc);
        }
    }

    // l_i: h-partner holds the other half of each j-subtile
    lsum += __shfl_xor(lsum, 32);
    const float s_lane = gamma[0] / lsum;

#pragma unroll
    for (int r = 0; r < 16; ++r) {
        const int row = (r & 3) + 8 * (r >> 2) + 4 * h;   // mfma32 D row
        const int c = c_blk + c_off + row;
        const int i = i0 + l31;                            // D col = i
        const size_t idx = ((size_t)b * CFEAT + c) * N_PIX + i;
        out[idx] = s_lane * acc[r] + features[idx];
    }
}

// ---------------------------------------------------------------------------
extern "C" void kernel_launch(void* const* d_in, const int* in_sizes, int n_in,
                              void* d_out, int out_size, void* d_ws, size_t ws_size,
                              hipStream_t stream) {
    const float* features   = (const float*)d_in[0];
    const float* conditions = (const float*)d_in[1];
    const float* Wq  = (const float*)d_in[2];
    const float* bq  = (const float*)d_in[3];
    const float* Wk  = (const float*)d_in[4];
    const float* bk  = (const float*)d_in[5];
    const float* Wv  = (const float*)d_in[6];
    const float* bv  = (const float*)d_in[7];
    const float* gam = (const float*)d_in[8];
    float* out = (float*)d_out;

    // ws (bf16): Qt 1MB | Kt 1MB | V 8MB
    bf16_t* Qt = (bf16_t*)d_ws;
    bf16_t* Kt = Qt + (size_t)NBATCH * N_PIX * CKEY;
    bf16_t* Vw = Kt + (size_t)NBATCH * N_PIX * CKEY;

    projqk_kernel<<<dim3(N_PIX / 64, 2, NBATCH), 256, 0, stream>>>(
        Wq, bq, conditions, Wk, bk, features, Qt, Kt);
    projv_kernel<<<dim3(N_PIX / 32, 2, NBATCH), 256, 0, stream>>>(Wv, bv, features, Vw);
    pv_kernel<<<dim3(4, N_PIX / 64, NBATCH), 256, 0, stream>>>(
        Qt, Kt, Vw, features, gam, out);
}

// Round 9
// 235.733 us; speedup vs baseline: 1.0437x; 1.0437x over previous
//
#include <hip/hip_runtime.h>

typedef __bf16 bf16_t;
typedef __bf16 bf16x2 __attribute__((ext_vector_type(2)));
typedef __bf16 bf16x8 __attribute__((ext_vector_type(8)));
typedef float f32x4 __attribute__((ext_vector_type(4)));
typedef float f32x16 __attribute__((ext_vector_type(16)));
typedef unsigned u32;
typedef unsigned u32x4 __attribute__((ext_vector_type(4)));

#define N_PIX 4096
#define CFEAT 256
#define CKEY 32
#define NBATCH 4
#define LOG2E 1.4426950408889634f

static __device__ __forceinline__ f32x4 mfma16(bf16x8 a, bf16x8 b, f32x4 c) {
    return __builtin_amdgcn_mfma_f32_16x16x32_bf16(a, b, c, 0, 0, 0);
}
static __device__ __forceinline__ f32x16 mfma32(bf16x8 a, bf16x8 b, f32x16 c) {
    return __builtin_amdgcn_mfma_f32_32x32x16_bf16(a, b, c, 0, 0, 0);
}
static __device__ __forceinline__ void glds16(const void* g, void* l) {
    __builtin_amdgcn_global_load_lds(
        (const __attribute__((address_space(1))) void*)g,
        (__attribute__((address_space(3))) void*)l, 16, 0, 0);
}
static __device__ __forceinline__ float fexp2(float x) {
#if __has_builtin(__builtin_amdgcn_exp2f)
    return __builtin_amdgcn_exp2f(x);
#else
    return exp2f(x);
#endif
}
static __device__ __forceinline__ u32 pack2(float a, float b) {
    bf16x2 t; t[0] = (bf16_t)a; t[1] = (bf16_t)b;
    return __builtin_bit_cast(u32, t);
}
// Swap the high 32 lanes of a with the low 32 lanes of b (the D->B-operand
// half-exchange for mfma32): new_a = [a(0:31), b(0:31)], new_b = [a(32:63), b(32:63)].
static __device__ __forceinline__ void halfswap(u32& a, u32& b) {
#if __has_builtin(__builtin_amdgcn_permlane32_swap)
    auto r = __builtin_amdgcn_permlane32_swap(a, b, false, false);
    a = r[0]; b = r[1];
#else
    const bool hi = ((threadIdx.x & 63) >= 32);
    u32 xa = (u32)__shfl_xor((int)a, 32);
    u32 xb = (u32)__shfl_xor((int)b, 32);
    a = hi ? xb : a;
    b = hi ? b : xa;
#endif
}

// ---------------------------------------------------------------------------
// projqk (r5 + log2e fold on Q): Yt[b][n][32] = bf16(scale*(W.X + bias)).
// grid (N/64, 2, B), block 256. LDS repack -> coalesced 16B stores.
// ---------------------------------------------------------------------------
__global__ __launch_bounds__(256) void projqk_kernel(
    const float* __restrict__ Wq, const float* __restrict__ bq, const float* __restrict__ Xq,
    const float* __restrict__ Wk, const float* __restrict__ bk, const float* __restrict__ Xk,
    bf16_t* __restrict__ Qt, bf16_t* __restrict__ Kt)
{
    __shared__ __attribute__((aligned(16))) bf16_t T[64][40];
    const int lane = threadIdx.x & 63, wave = threadIdx.x >> 6;
    const int g = lane >> 4, ln = lane & 15;
    const bool isK = (blockIdx.y == 1);
    const float* W    = isK ? Wk : Wq;
    const float* bias = isK ? bk : bq;
    const float scale = isK ? 1.0f : LOG2E;
    const float* X  = (isK ? Xk : Xq) + (size_t)blockIdx.z * CFEAT * N_PIX;
    bf16_t*      Yt = (isK ? Kt : Qt) + (size_t)blockIdx.z * N_PIX * CKEY;

    const int m_base = (wave & 1) * 16;
    const int n_loc  = (wave >> 1) * 32;
    const int n_base = blockIdx.x * 64 + n_loc;

    f32x4 zero = {0.f, 0.f, 0.f, 0.f};
    f32x4 acc[2] = {zero, zero};
    for (int k0 = 0; k0 < CFEAT; k0 += 32) {
        bf16x8 a;
        const float* wp = W + (size_t)(m_base + ln) * CFEAT + k0 + g * 8;
#pragma unroll
        for (int j = 0; j < 8; ++j) a[j] = (bf16_t)wp[j];
#pragma unroll
        for (int nt = 0; nt < 2; ++nt) {
            const float* xp = X + (size_t)(k0 + g * 8) * N_PIX + n_base + nt * 16 + ln;
            bf16x8 bfr;
#pragma unroll
            for (int j = 0; j < 8; ++j) bfr[j] = (bf16_t)xp[(size_t)j * N_PIX];
            acc[nt] = mfma16(a, bfr, acc[nt]);
        }
    }
#pragma unroll
    for (int nt = 0; nt < 2; ++nt)
#pragma unroll
        for (int r = 0; r < 4; ++r) {
            const int ck = m_base + g * 4 + r;
            T[n_loc + nt * 16 + ln][ck] = (bf16_t)((acc[nt][r] + bias[ck]) * scale);
        }
    __syncthreads();
    const int n  = threadIdx.x >> 2;
    const int sg = threadIdx.x & 3;
    bf16x8 row = *(const bf16x8*)&T[n][sg * 8];
    *(bf16x8*)&Yt[(size_t)(blockIdx.x * 64 + n) * CKEY + sg * 8] = row;
}

// ---------------------------------------------------------------------------
// projv (r5 verbatim): V[b][c][n] = bf16(Wv.X + bv). grid (N/32, 2, B).
// ---------------------------------------------------------------------------
__global__ __launch_bounds__(256, 4) void projv_kernel(
    const float* __restrict__ W, const float* __restrict__ bias,
    const float* __restrict__ X, bf16_t* __restrict__ V)
{
    const int lane = threadIdx.x & 63, wave = threadIdx.x >> 6;
    const int g = lane >> 4, ln = lane & 15;
    const int b = blockIdx.z;
    const int n_base = blockIdx.x * 32;
    const int c_wave = blockIdx.y * 128 + wave * 32;
    const float* Xb = X + (size_t)b * CFEAT * N_PIX;
    bf16_t*      Vb = V + (size_t)b * CFEAT * N_PIX;

    f32x4 zero = {0.f, 0.f, 0.f, 0.f};
    f32x4 acc[2][2];
#pragma unroll
    for (int mt = 0; mt < 2; ++mt) { acc[mt][0] = zero; acc[mt][1] = zero; }

    for (int k0 = 0; k0 < CFEAT; k0 += 32) {
        bf16x8 bfr[2];
#pragma unroll
        for (int nt = 0; nt < 2; ++nt) {
            const float* xp = Xb + (size_t)(k0 + g * 8) * N_PIX + n_base + nt * 16 + ln;
#pragma unroll
            for (int j = 0; j < 8; ++j) bfr[nt][j] = (bf16_t)xp[(size_t)j * N_PIX];
        }
#pragma unroll
        for (int mt = 0; mt < 2; ++mt) {
            const float* wp = W + (size_t)(c_wave + mt * 16 + ln) * CFEAT + k0 + g * 8;
            bf16x8 a;
#pragma unroll
            for (int j = 0; j < 8; ++j) a[j] = (bf16_t)wp[j];
            acc[mt][0] = mfma16(a, bfr[0], acc[mt][0]);
            acc[mt][1] = mfma16(a, bfr[1], acc[mt][1]);
        }
    }
#pragma unroll
    for (int mt = 0; mt < 2; ++mt)
#pragma unroll
        for (int nt = 0; nt < 2; ++nt)
#pragma unroll
            for (int r = 0; r < 4; ++r) {
                const int m = c_wave + mt * 16 + g * 4 + r;
                const int n = n_base + nt * 16 + ln;
                Vb[(size_t)m * N_PIX + n] = (bf16_t)(acc[mt][nt][r] + bias[m]);
            }
}

// ---------------------------------------------------------------------------
// pv: out = gamma * softmax(QK^T).V / l + feat (max-free, exp2; Q pre-scaled).
// r5 shape (block 64i x 128c, wave 32i x 64c, grid (2, N/64, B) = 512 blocks,
// M=4, 8 waves/CU) + all-mfma32 + REGISTER-HELD P:
// exp(S^T) D-frags are converted to PV B-frags with v_permlane32_swap
// (fallback shfl_xor) -- NO P LDS traffic at all.
// V tile 128c x 64j staged via glds16 chunk-major [jc][c], double-buffered,
// glds issued after the per-iter barrier. K/Q frags direct global (L2-hot).
// ---------------------------------------------------------------------------
__global__ __launch_bounds__(256) void pv_kernel(
    const bf16_t* __restrict__ Qt, const bf16_t* __restrict__ Kt,
    const bf16_t* __restrict__ V,
    const float* __restrict__ features, const float* __restrict__ gamma,
    float* __restrict__ out)
{
    __shared__ __attribute__((aligned(16))) bf16_t Vlds[2][128 * 64]; // 2 x 16KB

    const int lane = threadIdx.x & 63, wave = threadIdx.x >> 6;
    const int l31 = lane & 31, h = lane >> 5;
    const int iw = wave & 1, cw = wave >> 1;
    const int b = blockIdx.z;
    const int i0 = blockIdx.y * 64 + iw * 32;      // wave's 32 i
    const int c_blk = blockIdx.x * 128;
    const int c_off = cw * 64;                     // wave's 64 c within tile

    const bf16_t* Qb = Qt + (size_t)b * N_PIX * CKEY;
    const bf16_t* Kb = Kt + (size_t)b * N_PIX * CKEY;
    const bf16_t* Vb = V + (size_t)b * CFEAT * N_PIX;

    // Q B-frags (hoisted): B[k=16s+8h+t][n=i=l31] = Qt[i][ck]
    bf16x8 qf[2];
#pragma unroll
    for (int s = 0; s < 2; ++s)
        qf[s] = *(const bf16x8*)&Qb[(size_t)(i0 + l31) * CKEY + s * 16 + h * 8];

    // V staging map (r7's, c=128): slot = q*256 + wave*64 + lane;
    // c = slot & 127, jc = slot >> 7; LDS elem = slot*8 (base wave-uniform).
    const bf16_t* vsrc[4];
#pragma unroll
    for (int q = 0; q < 4; ++q) {
        const int slot = q * 256 + wave * 64 + lane;
        vsrc[q] = Vb + (size_t)(c_blk + (slot & 127)) * N_PIX + (slot >> 7) * 8;
    }

    f32x16 acc[2];
#pragma unroll
    for (int ct = 0; ct < 2; ++ct)
#pragma unroll
        for (int r = 0; r < 16; ++r) acc[ct][r] = 0.f;
    float lsum = 0.f;

    // prologue: stage V(0) -> buf 0
#pragma unroll
    for (int q = 0; q < 4; ++q)
        glds16(vsrc[q], &Vlds[0][(q * 256 + wave * 64) * 8]);

    for (int n = 0; n < 64; ++n) {
        const int j0 = n * 64;
        // ---- S^T(n): 2 j-subtiles of 32j x 32i, ck=32 = 2 mfma32 steps ----
        bf16x8 pb[4];   // PV B-frags for k-steps ks=0..3 (j = 16ks..16ks+15)
#pragma unroll
        for (int jsub = 0; jsub < 2; ++jsub) {
            const bf16_t* kp = &Kb[(size_t)(j0 + jsub * 32 + l31) * CKEY + h * 8];
            const bf16x8 kf0 = *(const bf16x8*)kp;          // ck = 8h+t
            const bf16x8 kf1 = *(const bf16x8*)(kp + 16);   // ck = 16+8h+t
            f32x16 z;
#pragma unroll
            for (int r = 0; r < 16; ++r) z[r] = 0.f;
            f32x16 st = mfma32(kf1, qf[1], mfma32(kf0, qf[0], z));
            // exp2 + pack: reg r holds (j_loc = 32*jsub + (r&3)+8*(r>>2)+4h, i=l31)
            float e[16];
#pragma unroll
            for (int r = 0; r < 16; ++r) { e[r] = fexp2(st[r]); lsum += e[r]; }
            u32 p0a = pack2(e[0], e[1]),   p0b = pack2(e[2], e[3]);
            u32 p1a = pack2(e[4], e[5]),   p1b = pack2(e[6], e[7]);
            u32 p2a = pack2(e[8], e[9]),   p2b = pack2(e[10], e[11]);
            u32 p3a = pack2(e[12], e[13]), p3b = pack2(e[14], e[15]);
            // D-layout -> B-operand layout: exchange lane-halves
            halfswap(p0a, p1a); halfswap(p0b, p1b);
            halfswap(p2a, p3a); halfswap(p2b, p3b);
            pb[2 * jsub]     = __builtin_bit_cast(bf16x8, (u32x4){p0a, p0b, p1a, p1b});
            pb[2 * jsub + 1] = __builtin_bit_cast(bf16x8, (u32x4){p2a, p2b, p3a, p3b});
        }

        // ---- barrier: drains V(n) DMA; then issue V(n+1) ----
        __syncthreads();
        const int jn = (j0 + 64) & (N_PIX - 1);   // wrap on last iter: unused
        const int bn = (n + 1) & 1;
#pragma unroll
        for (int q = 0; q < 4; ++q)
            glds16(vsrc[q] + jn, &Vlds[bn][(q * 256 + wave * 64) * 8]);

        // ---- PV(n): A = V chunk (jc = 2ks+h, c = c_off + 32*ct + l31) ----
        const bf16_t* Vt = &Vlds[n & 1][0];
#pragma unroll
        for (int ks = 0; ks < 4; ++ks) {
#pragma unroll
            for (int ct = 0; ct < 2; ++ct) {
                const bf16x8 va = *(const bf16x8*)
                    &Vt[((2 * ks + h) * 128 + c_off + ct * 32 + l31) * 8];
                acc[ct] = mfma32(va, pb[ks], acc[ct]);
            }
        }
    }

    // l_i: lane (l31,h) summed j with ((j>>2)&1)==h; partner has the rest
    lsum += __shfl_xor(lsum, 32);
    const float s_lane = gamma[0] / lsum;

#pragma unroll
    for (int ct = 0; ct < 2; ++ct)
#pragma unroll
        for (int r = 0; r < 16; ++r) {
            const int row = (r & 3) + 8 * (r >> 2) + 4 * h;   // mfma32 D row
            const int c = c_blk + c_off + ct * 32 + row;
            const int i = i0 + l31;                           // D col = i
            const size_t idx = ((size_t)b * CFEAT + c) * N_PIX + i;
            out[idx] = s_lane * acc[ct][r] + features[idx];
        }
}

// ---------------------------------------------------------------------------
extern "C" void kernel_launch(void* const* d_in, const int* in_sizes, int n_in,
                              void* d_out, int out_size, void* d_ws, size_t ws_size,
                              hipStream_t stream) {
    const float* features   = (const float*)d_in[0];
    const float* conditions = (const float*)d_in[1];
    const float* Wq  = (const float*)d_in[2];
    const float* bq  = (const float*)d_in[3];
    const float* Wk  = (const float*)d_in[4];
    const float* bk  = (const float*)d_in[5];
    const float* Wv  = (const float*)d_in[6];
    const float* bv  = (const float*)d_in[7];
    const float* gam = (const float*)d_in[8];
    float* out = (float*)d_out;

    // ws (bf16): Qt 1MB | Kt 1MB | V 8MB
    bf16_t* Qt = (bf16_t*)d_ws;
    bf16_t* Kt = Qt + (size_t)NBATCH * N_PIX * CKEY;
    bf16_t* Vw = Kt + (size_t)NBATCH * N_PIX * CKEY;

    projqk_kernel<<<dim3(N_PIX / 64, 2, NBATCH), 256, 0, stream>>>(
        Wq, bq, conditions, Wk, bk, features, Qt, Kt);
    projv_kernel<<<dim3(N_PIX / 32, 2, NBATCH), 256, 0, stream>>>(Wv, bv, features, Vw);
    pv_kernel<<<dim3(2, N_PIX / 64, NBATCH), 256, 0, stream>>>(
        Qt, Kt, Vw, features, gam, out);
}